// Round 1
// baseline (338.073 us; speedup 1.0000x reference)
//
#include <hip/hip_runtime.h>
#include <math.h>
#include <string.h>

#define TILE    32
#define HALO    9
#define IN_T    (TILE + 2*HALO)     /* 50 */
#define IMG_H   512
#define IMG_W   512
#define NPIX    (IMG_H*IMG_W)       /* 262144 = 1<<18 */
#define NIMG    16
#define NSIG    5
#define MAXL    19
#define MIN_SZ  200
#define TSTRIDE 51                  /* padded LDS stride for t-arrays (max WV=50, +1 odd) */

struct Taps {
  float k[NSIG][3][MAXL];
  float s2[NSIG];
  int   rad[NSIG];
};

// ---------------------------------------------------------------------------
// Frangi: per-sigma separable Hessian + vesselness, fully in LDS/registers.
// Conv convention (matches reference _corr1d == convolution with k):
//   y[i] = sum_j x[i + j - rad] * k[L-1-j],  j ascending.
// ---------------------------------------------------------------------------
template<int RAD>
__device__ __forceinline__ void do_sigma(const float* __restrict__ sIn,
                                         float* __restrict__ t0,
                                         float* __restrict__ t1,
                                         float* __restrict__ t2,
                                         const float (* __restrict__ sK3)[MAXL],
                                         float s2, int tid, float* fr)
{
  constexpr int L     = 2*RAD + 1;
  constexpr int WV    = TILE + 2*RAD;          // vertical-pass output width
  constexpr int NPOS  = TILE * WV;
  constexpr int NSLOT = (NPOS + 255) / 256;

  // ---- vertical pass (along rows / axis 1) -> t0(k0), t1(k1), t2(k2) ----
  float a0[NSLOT], a1[NSLOT], a2[NSLOT];
  int   adr[NSLOT];
  int   tps[NSLOT];
#pragma unroll
  for (int i = 0; i < NSLOT; ++i) {
    int pos = tid + i*256;
    bool v = (pos < NPOS);
    int r = pos / WV;
    int c = pos - r*WV;                        // t-array col; tile col = c-RAD
    a0[i] = a1[i] = a2[i] = 0.0f;
    adr[i] = v ? ((r + HALO - RAD)*IN_T + (c + HALO - RAD)) : 0;
    tps[i] = v ? (r*TSTRIDE + c) : -1;
  }
#pragma unroll 1
  for (int j = 0; j < L; ++j) {
    float w0 = sK3[0][L-1-j];
    float w1 = sK3[1][L-1-j];
    float w2 = sK3[2][L-1-j];
#pragma unroll
    for (int i = 0; i < NSLOT; ++i) {
      float x = sIn[adr[i] + j*IN_T];
      a0[i] += x*w0;
      a1[i] += x*w1;
      a2[i] += x*w2;
    }
  }
#pragma unroll
  for (int i = 0; i < NSLOT; ++i) {
    if (tps[i] >= 0) { t0[tps[i]] = a0[i]; t1[tps[i]] = a1[i]; t2[tps[i]] = a2[i]; }
  }
  __syncthreads();

  // ---- horizontal pass + vesselness; thread -> row r, 4 consecutive cols ----
  {
    int r    = tid >> 3;
    int c0   = (tid & 7) * 4;
    int base = r*TSTRIDE + c0;
    float hrr[4] = {0,0,0,0}, hrc[4] = {0,0,0,0}, hcc[4] = {0,0,0,0};
    float u0[4], u1[4], u2[4];                 // sliding window t[c0+j .. c0+j+3]
#pragma unroll
    for (int k = 0; k < 4; ++k) { u0[k] = t0[base+k]; u1[k] = t1[base+k]; u2[k] = t2[base+k]; }
#pragma unroll 1
    for (int j = 0; j < L; ++j) {
      float w0 = sK3[0][L-1-j];
      float w1 = sK3[1][L-1-j];
      float w2 = sK3[2][L-1-j];
#pragma unroll
      for (int k = 0; k < 4; ++k) {
        hrr[k] += u2[k]*w0;                    // Hrr = vert k2 (.) horiz k0
        hrc[k] += u1[k]*w1;                    // Hrc = vert k1 (.) horiz k1
        hcc[k] += u0[k]*w2;                    // Hcc = vert k0 (.) horiz k2
      }
      if (j < L-1) {
#pragma unroll
        for (int k = 0; k < 3; ++k) { u0[k] = u0[k+1]; u1[k] = u1[k+1]; u2[k] = u2[k+1]; }
        u0[3] = t0[base + j + 4];
        u1[3] = t1[base + j + 4];
        u2[3] = t2[base + j + 4];
      }
    }
#pragma unroll
    for (int k = 0; k < 4; ++k) {
      float Hrr = hrr[k]*s2, Hrc = hrc[k]*s2, Hcc = hcc[k]*s2;
      float mid  = 0.5f*(Hrr + Hcc);
      float dif  = 0.5f*(Hrr - Hcc);
      float disc = sqrtf(dif*dif + Hrc*Hrc);
      float ehi  = mid + disc;
      float elo  = mid - disc;
      bool  sm   = fabsf(ehi) <= fabsf(elo);
      float lam1 = sm ? ehi : elo;
      float lam2 = sm ? elo : ehi;
      float lam2c = fmaxf(lam2, 1e-10f);
      float q    = lam1 / lam2c;
      float rb2  = q*q;
      float ssq  = lam1*lam1 + lam2*lam2;
      float v    = expf((-rb2)/2.0f) * (1.0f - expf((-ssq)/50.0f));
      fr[k] = fmaxf(fr[k], v);
    }
  }
  __syncthreads();                              // t-arrays free for next sigma
}

__global__ __launch_bounds__(256)
void frangi_label_kernel(const float* __restrict__ img,
                         int* __restrict__ labels,
                         int* __restrict__ sizes,
                         Taps taps)
{
  __shared__ float sIn[IN_T*IN_T];
  __shared__ float t0[TILE*TSTRIDE];
  __shared__ float t1[TILE*TSTRIDE];
  __shared__ float t2[TILE*TSTRIDE];
  __shared__ float sK[NSIG][3][MAXL];

  const int tid = threadIdx.x;
  for (int i = tid; i < NSIG*3*MAXL; i += 256)
    ((float*)sK)[i] = ((const float*)taps.k)[i];

  const int imgIdx = blockIdx.y;
  const int tIdx   = blockIdx.x;
  const int tr0    = (tIdx >> 4) * TILE;
  const int tc0    = (tIdx & 15) * TILE;
  const float* __restrict__ im = img + (size_t)imgIdx * NPIX;

  // load halo tile: reflect ('symmetric') padding, negate+scale: -(x*500)
  for (int i = tid; i < IN_T*IN_T; i += 256) {
    int r = i / IN_T;
    int c = i - r*IN_T;
    int gr = tr0 - HALO + r;
    int gc = tc0 - HALO + c;
    gr = (gr < 0) ? (-1 - gr) : ((gr >= IMG_H) ? (2*IMG_H - 1 - gr) : gr);
    gc = (gc < 0) ? (-1 - gc) : ((gc >= IMG_W) ? (2*IMG_W - 1 - gc) : gc);
    sIn[i] = -(im[gr*IMG_W + gc] * 500.0f);
  }
  __syncthreads();

  float fr[4] = {0.0f, 0.0f, 0.0f, 0.0f};
  do_sigma<4>(sIn, t0, t1, t2, sK[0], taps.s2[0], tid, fr);   // sigma 1.0
  do_sigma<5>(sIn, t0, t1, t2, sK[1], taps.s2[1], tid, fr);   // sigma 1.3
  do_sigma<6>(sIn, t0, t1, t2, sK[2], taps.s2[2], tid, fr);   // sigma 1.6
  do_sigma<8>(sIn, t0, t1, t2, sK[3], taps.s2[3], tid, fr);   // sigma 1.9
  do_sigma<9>(sIn, t0, t1, t2, sK[4], taps.s2[4], tid, fr);   // sigma 2.2

  const int r  = tid >> 3;
  const int c0 = (tid & 7) * 4;
  const int gr = tr0 + r;
  const size_t imgBase = (size_t)imgIdx * NPIX;
#pragma unroll
  for (int k = 0; k < 4; ++k) {
    int p = gr*IMG_W + tc0 + c0 + k;
    float x = im[p];
    bool m = (x >= 0.1f) && (x <= 0.5f) && (fr[k] >= 0.2f);
    labels[imgBase + p] = m ? p : -1;
    sizes[imgBase + p]  = 0;
  }
}

// ---------------------------------------------------------------------------
// 8-connected CCL: atomic union-find (min-index root), then size filter.
// Agent-scope atomic loads: per-XCD L2s are not coherent for plain loads.
// ---------------------------------------------------------------------------
__device__ __forceinline__ int ldA(const int* p) {
  return __hip_atomic_load(p, __ATOMIC_RELAXED, __HIP_MEMORY_SCOPE_AGENT);
}
__device__ __forceinline__ int rootOf(const int* L, int x) {
  int pa = ldA(&L[x]);
  while (pa != x) { int g = ldA(&L[pa]); x = pa; pa = g; }
  return x;
}

__global__ __launch_bounds__(256)
void merge_kernel(int* __restrict__ labels)
{
  int gid = blockIdx.x*256 + threadIdx.x;
  int img = gid >> 18;
  int p   = gid & (NPIX - 1);
  int* L  = labels + ((size_t)img << 18);
  if (L[p] < 0) return;                        // background (sign never changes in K2)
  int r = p >> 9, c = p & (IMG_W - 1);
  const int dr[4] = {0,-1,-1,-1};
  const int dc[4] = {-1,-1,0,1};
#pragma unroll
  for (int k = 0; k < 4; ++k) {
    int nr = r + dr[k], nc = c + dc[k];
    if (nr < 0 || nc < 0 || nc >= IMG_W) continue;
    int q = (nr << 9) | nc;
    if (L[q] < 0) continue;
    int a = p, b = q;
    while (true) {
      a = rootOf(L, a);
      b = rootOf(L, b);
      if (a == b) break;
      int hi = a > b ? a : b;
      int lo = a < b ? a : b;
      int old = atomicCAS(&L[hi], hi, lo);     // link high root under low root
      if (old == hi) break;
      a = old; b = lo;
    }
  }
}

__global__ __launch_bounds__(256)
void compress_kernel(int* __restrict__ labels)
{
  int gid = blockIdx.x*256 + threadIdx.x;
  int img = gid >> 18;
  int p   = gid & (NPIX - 1);
  int* L  = labels + ((size_t)img << 18);
  if (L[p] < 0) return;
  int rt = rootOf(L, p);
  __hip_atomic_store(&L[p], rt, __ATOMIC_RELAXED, __HIP_MEMORY_SCOPE_AGENT);
}

__global__ __launch_bounds__(256)
void count_kernel(const int* __restrict__ labels, int* __restrict__ sizes)
{
  int gid  = blockIdx.x*256 + threadIdx.x;
  int l    = labels[gid];                      // root (min index) or -1
  int lane = threadIdx.x & 63;
  int left = __shfl_up(l, 1);
  bool head = (lane == 0) || (left != l);
  unsigned long long hb = __ballot(head);
  if (l >= 0 && head) {
    unsigned long long rest = (hb >> 1) >> lane;   // heads strictly above this lane
    int len = rest ? __ffsll((long long)rest) : (64 - lane);
    int img = gid >> 18;
    atomicAdd(&sizes[((size_t)img << 18) + l], len);
  }
}

__global__ __launch_bounds__(256)
void output_kernel(const int* __restrict__ labels, const int* __restrict__ sizes,
                   float* __restrict__ out)
{
  int gid = blockIdx.x*256 + threadIdx.x;
  int l = labels[gid];
  float v = 0.0f;
  if (l >= 0) {
    int img = gid >> 18;
    v = (sizes[((size_t)img << 18) + l] >= MIN_SZ) ? 1.0f : 0.0f;
  }
  out[gid] = v;
}

// ---------------------------------------------------------------------------
// Host: scipy.ndimage-style Gaussian derivative kernels (truncate=4), in
// double exactly as numpy computes them, cast to f32.
// ---------------------------------------------------------------------------
static void gauss1d(double sigma, int order, int rad, float* out)
{
  int L = 2*rad + 1;
  double phi[MAXL];
  double s = 0.0;
  for (int i = 0; i < L; ++i) {
    double x = (double)(i - rad);
    phi[i] = exp(-0.5*x*x/(sigma*sigma));
    s += phi[i];
  }
  for (int i = 0; i < L; ++i) phi[i] /= s;
  if (order == 0) {
    for (int i = 0; i < L; ++i) out[i] = (float)phi[i];
    return;
  }
  double q[3] = {1.0, 0.0, 0.0};
  for (int it = 0; it < order; ++it) {
    double nq[3] = {0.0, 0.0, 0.0};
    for (int i = 0; i <= order; ++i) {
      double v = 0.0;
      if (i+1 <= order) v += (double)(i+1) * q[i+1];        // D superdiag
      if (i-1 >= 0)     v += (-1.0/(sigma*sigma)) * q[i-1]; // P subdiag
      nq[i] = v;
    }
    q[0] = nq[0]; q[1] = nq[1]; q[2] = nq[2];
  }
  for (int i = 0; i < L; ++i) {
    double x = (double)(i - rad);
    double poly = q[0];
    double xp = x;
    for (int e = 1; e <= order; ++e) { poly += xp*q[e]; xp *= x; }
    out[i] = (float)(poly*phi[i]);
  }
}

extern "C" void kernel_launch(void* const* d_in, const int* in_sizes, int n_in,
                              void* d_out, int out_size, void* d_ws, size_t ws_size,
                              hipStream_t stream)
{
  (void)in_sizes; (void)n_in; (void)out_size; (void)ws_size;
  const float* img = (const float*)d_in[0];
  float* out = (float*)d_out;
  // workspace layout: labels[16*2^18] int, sizes[16*2^18] int  (32 MiB total)
  int* labels = (int*)d_ws;
  int* sizes  = labels + (size_t)NIMG * NPIX;

  Taps taps;
  memset(&taps, 0, sizeof(taps));
  for (int s = 0; s < NSIG; ++s) {
    double sigma = 1.0 + 0.3 * (double)s;      // np.arange(1.0, 2.5, 0.3)
    int rad = (int)(4.0 * sigma + 0.5);        // 4,5,6,8,9 (matches templates)
    taps.rad[s] = rad;
    taps.s2[s]  = (float)(sigma * sigma);
    for (int o = 0; o < 3; ++o) gauss1d(sigma, o, rad, taps.k[s][o]);
  }

  dim3 gridF(NPIX / (TILE*TILE), NIMG);        // 256 tiles x 16 images
  frangi_label_kernel<<<gridF, 256, 0, stream>>>(img, labels, sizes, taps);

  int blocks = (NIMG * NPIX) / 256;            // 16384
  merge_kernel   <<<blocks, 256, 0, stream>>>(labels);
  compress_kernel<<<blocks, 256, 0, stream>>>(labels);
  count_kernel   <<<blocks, 256, 0, stream>>>(labels, sizes);
  output_kernel  <<<blocks, 256, 0, stream>>>(labels, sizes, out);
}